// Round 8
// baseline (312.452 us; speedup 1.0000x reference)
//
#include <hip/hip_runtime.h>
#include <math.h>

// Problem constants (fixed by setup_inputs)
constexpr int NB = 64;     // batch
constexpr int NT = 1024;   // time steps
constexpr int NV = 256;    // vocab
constexpr int NS = 256;    // target length (padded)
constexpr int NL = 2 * NS + 1;        // 513 extended CTC states
constexpr int NDG = NT + NS - 1;      // 1279 anti-diagonals
__device__ constexpr float BIGV = 1e10f;

using f32x4 = __attribute__((ext_vector_type(4))) float;
using s16x8 = __attribute__((ext_vector_type(8))) short;

// ---------------- DPP cross-lane helpers ----------------
__device__ __forceinline__ float dpp_shr1_f32(float x, float lane0val) {
    int r = __builtin_amdgcn_update_dpp(__float_as_int(lane0val),
                                        __float_as_int(x), 0x138, 0xf, 0xf, false);
    return __int_as_float(r);
}
__device__ __forceinline__ double dpp_shr1_zero_f64(double x) {
    union { double d; unsigned long long u; } c; c.d = x;
    int lo = (int)(c.u & 0xffffffffull), hi = (int)(c.u >> 32);
    int nlo = __builtin_amdgcn_update_dpp(0, lo, 0x138, 0xf, 0xf, true);
    int nhi = __builtin_amdgcn_update_dpp(0, hi, 0x138, 0xf, 0xf, true);
    c.u = ((unsigned long long)(unsigned)nhi << 32) | (unsigned)nlo;
    return c.d;
}
__device__ __forceinline__ int wave_imax_dpp(int x) {   // non-negative x
    int t;
    t = __builtin_amdgcn_update_dpp(0, x, 0x111, 0xf, 0xf, true); x = max(x, t);
    t = __builtin_amdgcn_update_dpp(0, x, 0x112, 0xf, 0xf, true); x = max(x, t);
    t = __builtin_amdgcn_update_dpp(0, x, 0x114, 0xf, 0xf, true); x = max(x, t);
    t = __builtin_amdgcn_update_dpp(0, x, 0x118, 0xf, 0xf, true); x = max(x, t);
    t = __builtin_amdgcn_update_dpp(0, x, 0x142, 0xf, 0xf, true); x = max(x, t);
    t = __builtin_amdgcn_update_dpp(0, x, 0x143, 0xf, 0xf, true); x = max(x, t);
    return __builtin_amdgcn_readlane(x, 63);
}
__device__ __forceinline__ float row16_sum(float x) {
    x += __int_as_float(__builtin_amdgcn_update_dpp(0, __float_as_int(x), 0x111, 0xf, 0xf, true));
    x += __int_as_float(__builtin_amdgcn_update_dpp(0, __float_as_int(x), 0x112, 0xf, 0xf, true));
    x += __int_as_float(__builtin_amdgcn_update_dpp(0, __float_as_int(x), 0x114, 0xf, 0xf, true));
    x += __int_as_float(__builtin_amdgcn_update_dpp(0, __float_as_int(x), 0x118, 0xf, 0xf, true));
    return x;
}
__device__ __forceinline__ unsigned short f2bf(float x) {   // round-to-nearest-even
    unsigned u = __float_as_uint(x);
    return (unsigned short)((u + 0x7fffu + ((u >> 16) & 1u)) >> 16);
}
__device__ __forceinline__ float bf2f(unsigned short h) {
    return __uint_as_float((unsigned)h << 16);
}

// ---------------------------------------------------------------------------
// K1 (MFMA): per block = 128 rows of one batch. Ddiag stored as BF16.
// 512 threads (8 waves). LDS caps occupancy at 1 block/CU.
// ---------------------------------------------------------------------------
__global__ __launch_bounds__(512, 1) void k_dmat(
    const float* __restrict__ lp, const float* __restrict__ fm,
    const int* __restrict__ tgt, unsigned short* __restrict__ Ddiag,
    unsigned short* __restrict__ Gbf, float* __restrict__ PB)
{
    constexpr int ESTR = 264;
    constexpr int FSTR = 264;
    constexpr int TSTR = 40;
    constexpr int PSTR = 40;
    constexpr int DSTR = 130;

    __shared__ __align__(16) unsigned char uni[128 * ESTR * 2];  // E / Dst union
    __shared__ __align__(16) unsigned short FT[32 * FSTR];
    __shared__ __align__(16) unsigned short tgf[256 * TSTR];
    __shared__ __align__(16) unsigned short pb16[128 * PSTR];
    __shared__ float tsq[256];
    __shared__ float psq[128];

    unsigned short* E = (unsigned short*)uni;
    float* Dst = (float*)uni;

    const int tid  = threadIdx.x;
    const int lane = tid & 63;
    const int w    = tid >> 6;          // 0..7
    const int b    = blockIdx.x >> 3;
    const int a0   = (blockIdx.x & 7) * 128;

    const int row2 = tid >> 1;          // 0..255 (vocab / target row)
    const int half = tid & 1;           // 0/1: cols 0..11 / 12..23
    const int k0   = half * 12;

    {   // FT: vocab feature matrix, bf16, transposed [k][v]
        const float* fr = fm + row2 * 24 + k0;
        #pragma unroll
        for (int k = 0; k < 12; k += 4) {
            float4 t4 = *(const float4*)(fr + k);
            FT[(k0 + k + 0) * FSTR + row2] = f2bf(t4.x);
            FT[(k0 + k + 1) * FSTR + row2] = f2bf(t4.y);
            FT[(k0 + k + 2) * FSTR + row2] = f2bf(t4.z);
            FT[(k0 + k + 3) * FSTR + row2] = f2bf(t4.w);
        }
        if (half) {
            #pragma unroll
            for (int n = 24; n < 32; ++n) FT[n * FSTR + row2] = 0;
        }
    }
    {   // tgf: target feature rows, bf16, row-major; tsq: their square sums
        const int lab_r = tgt[b * NS + row2];
        const float* fr = fm + lab_r * 24 + k0;
        float s = 0.f;
        #pragma unroll
        for (int k = 0; k < 12; k += 4) {
            float4 t4 = *(const float4*)(fr + k);
            unsigned p0 = f2bf(t4.x) | ((unsigned)f2bf(t4.y) << 16);
            unsigned p1 = f2bf(t4.z) | ((unsigned)f2bf(t4.w) << 16);
            *(unsigned*)&tgf[row2 * TSTR + k0 + k]     = p0;
            *(unsigned*)&tgf[row2 * TSTR + k0 + k + 2] = p1;
            s += t4.x * t4.x + t4.y * t4.y + t4.z * t4.z + t4.w * t4.w;
        }
        const float sf = s + __shfl_xor(s, 1);
        if (!half) tsq[row2] = sf;
        else {
            #pragma unroll
            for (int k = 24; k < 32; k += 2) *(unsigned*)&tgf[row2 * TSTR + k] = 0;
        }
    }
    const int lab2 = tgt[b * NS + (tid & 255)];   // for the Gbf gather below
    {   // E: exp(log_probs) for 128 time rows, bf16
        const float* src = lp + ((size_t)b * NT + a0) * NV;
        #pragma unroll
        for (int it = 0; it < 16; ++it) {
            int f4  = it * 512 + tid;
            int row = f4 >> 6;
            int c4  = f4 & 63;
            float4 v = *(const float4*)(src + row * NV + c4 * 4);
            float e0 = __expf(v.x), e1 = __expf(v.y);
            float e2 = __expf(v.z), e3 = __expf(v.w);
            unsigned* dst = (unsigned*)&E[row * ESTR + c4 * 4];
            dst[0] = f2bf(e0) | ((unsigned)f2bf(e1) << 16);
            dst[1] = f2bf(e2) | ((unsigned)f2bf(e3) << 16);
            if (c4 == 0) PB[b * NT + a0 + row] = e0;
        }
    }
    __syncthreads();

    {   // Gbf gather: per time row, prob of each target label (bf16)
        unsigned short* gd = Gbf + (((size_t)(b * NT + a0)) << 8) + (tid & 255);
        const int rbit = tid >> 8;                 // 0/1
        #pragma unroll 8
        for (int i = 0; i < 64; ++i) {
            int rr = (i << 1) | rbit;
            gd[(size_t)rr << 8] = E[rr * ESTR + lab2];
        }
    }

    // ---- MFMA-1: P = E(128x256) * FT^T(256x32)  (only 24 cols real) ----
    const int m0  = 16 * w;           // 16 rows per wave
    const int q   = lane >> 4;
    const int n16 = lane & 15;
    f32x4 acc00 = {0.f, 0.f, 0.f, 0.f}, acc01 = acc00;
    #pragma unroll
    for (int ks = 0; ks < 8; ++ks) {
        s16x8 a0f = *(const s16x8*)&E[(m0 + n16) * ESTR + ks * 32 + q * 8];
        s16x8 b0f = *(const s16x8*)&FT[(n16) * FSTR + ks * 32 + q * 8];
        s16x8 b1f = *(const s16x8*)&FT[(16 + n16) * FSTR + ks * 32 + q * 8];
        acc00 = __builtin_amdgcn_mfma_f32_16x16x32_bf16(a0f, b0f, acc00, 0, 0, 0);
        acc01 = __builtin_amdgcn_mfma_f32_16x16x32_bf16(a0f, b1f, acc01, 0, 0, 0);
    }
    #pragma unroll
    for (int r = 0; r < 4; ++r) {
        float s0 = acc00[r] * acc00[r] + acc01[r] * acc01[r];
        s0 = row16_sum(s0);
        if (n16 == 15) psq[m0 + 4 * q + r] = s0;
        pb16[(m0 + 4 * q + r) * PSTR + n16]      = f2bf(acc00[r]);
        pb16[(m0 + 4 * q + r) * PSTR + 16 + n16] = f2bf(acc01[r]);
    }

    // ---- per h: Dst = |P|^2 + |T|^2 - 2 P T^T, then diagonal extraction ----
    #pragma unroll 1
    for (int h = 0; h < 2; ++h) {
        __syncthreads();
        s16x8 pa0 = *(const s16x8*)&pb16[(m0 + n16) * PSTR + q * 8];
        float ps0[4];
        #pragma unroll
        for (int r = 0; r < 4; ++r) ps0[r] = psq[m0 + 4 * q + r];
        #pragma unroll
        for (int nt = 0; nt < 8; ++nt) {
            const int j0 = 16 * nt;
            s16x8 tb = *(const s16x8*)&tgf[(128 * h + j0 + n16) * TSTR + q * 8];
            float tq = tsq[128 * h + j0 + n16];
            f32x4 z = {0.f, 0.f, 0.f, 0.f};
            f32x4 d0 = __builtin_amdgcn_mfma_f32_16x16x32_bf16(pa0, tb, z, 0, 0, 0);
            #pragma unroll
            for (int r = 0; r < 4; ++r)
                Dst[(m0 + 4 * q + r) * DSTR + j0 + n16] = ps0[r] + tq - 2.f * d0[r];
        }
        __syncthreads();
        // anti-diagonal extraction; dp = 8*i + w covers 0..255
        const size_t dbase = ((size_t)b * NDG + a0 + 128 * h) * NS + 128 * h;
        #pragma unroll 4
        for (int i = 0; i < 32; ++i) {
            int dp  = 8 * i + w;
            int jlo = dp > 127 ? dp - 127 : 0;
            int jhi = dp < 127 ? dp : 127;
            #pragma unroll
            for (int c = 0; c < 2; ++c) {
                int jj = jlo + 64 * c + lane;
                if (jj <= jhi) {
                    unsigned short vv = f2bf(Dst[(dp - jj) * DSTR + jj]);
                    Ddiag[dbase + (size_t)dp * NS + jj] = vv;
                }
            }
        }
    }
}

// ---------------------------------------------------------------------------
// K2 (fast): exact R2 structure, fp32 arithmetic only. blocks 0..63: CTC
// fp32 (rescale target 2^100, cadence 4 — numerics verified in R7 which
// passed end-to-end); on flush the block writes flags[b]=1 and k_dp_fix
// redoes it exactly in fp64. No fp64 code in this kernel => register
// allocator keeps the depth-32 queue in VGPRs (R7's co-compiled giant
// function rerolled it to scratch: VGPR 84->72, 2x dur).
// blocks 64..127: SoftDTW hard-min wavefront (unchanged, verified).
// ---------------------------------------------------------------------------
__global__ __launch_bounds__(64, 1) void k_dp(
    const float* __restrict__ lp, const int* __restrict__ tgt,
    const int* __restrict__ ilen, const int* __restrict__ tlen,
    const unsigned short* __restrict__ Ddiag, const unsigned short* __restrict__ Gbf,
    const float* __restrict__ PB, float* __restrict__ ctc_out,
    float* __restrict__ sdtw_out, int* __restrict__ flags)
{
    __shared__ float smf[513];
    const int lane = threadIdx.x;
    const int bid = blockIdx.x;

    if (bid < NB) {
        // ------------------------- CTC, linear fp32 -------------------------
        const int b  = bid;
        const int len = ilen[b];          // wave-uniform (768..1024)
        const int tl  = tlen[b];
        const float* lpb = lp + (size_t)b * NT * NV;
        const unsigned short* Gb = Gbf + ((size_t)(b * NT) << 8);
        const float* PBb = PB + b * NT;

        const int4 t4 = ((const int4*)(tgt + b * NS))[lane];
        const int prevw = __shfl_up(t4.w, 1);
        const float m1 = ((lane > 0) && (t4.x != prevw)) ? 1.0f : 0.0f;
        const float m3 = (t4.y != t4.x) ? 1.0f : 0.0f;
        const float m5 = (t4.z != t4.y) ? 1.0f : 0.0f;
        const float m7 = (t4.w != t4.z) ? 1.0f : 0.0f;

        float a0 = 0.f, a1 = 0.f, a2 = 0.f, a3 = 0.f, a4 = 0.f,
              a5 = 0.f, a6 = 0.f, a7 = 0.f, a8 = 0.f;
        if (lane == 0) {
            a0 = __expf(lpb[0]);
            a1 = __expf(lpb[t4.x]);
        }
        int Ks = 0;

        auto ctc_step = [&](const ushort4 gu, const float pbf) {
            const float pb = pbf;
            const float p0 = bf2f(gu.x), p1 = bf2f(gu.y);
            const float p2 = bf2f(gu.z), p3 = bf2f(gu.w);
            const float l7 = dpp_shr1_f32(a7, 0.0f);
            const float n0 = (a0 + l7) * pb;
            const float n1 = fmaf(m1, l7, a1 + a0) * p0;
            const float n2 = (a2 + a1) * pb;
            const float n3 = fmaf(m3, a1, a3 + a2) * p1;
            const float n4 = (a4 + a3) * pb;
            const float n5 = fmaf(m5, a3, a5 + a4) * p2;
            const float n6 = (a6 + a5) * pb;
            const float n7 = fmaf(m7, a5, a7 + a6) * p3;
            const float n8 = (a8 + a7) * pb;
            a0 = n0; a1 = n1; a2 = n2; a3 = n3; a4 = n4;
            a5 = n5; a6 = n6; a7 = n7; a8 = n8;
        };
        // rescale so wave max lands at 2^100 (biased 227); exact pow2 only.
        auto ctc_rescale = [&]() {
            float m = fmaxf(a0, a1);
            m = fmaxf(m, a2); m = fmaxf(m, a3); m = fmaxf(m, a4);
            m = fmaxf(m, a5); m = fmaxf(m, a6); m = fmaxf(m, a7);
            m = fmaxf(m, a8);
            int Eb = (int)((__float_as_uint(m) >> 23) & 0xffu);
            int Ex = wave_imax_dpp(Eb);
            if (Ex < 1) Ex = 1;
            int sh = 227 - Ex; if (sh > 127) sh = 127;   // sh in [-27,127]
            const float sc = __uint_as_float((unsigned)(127 + sh) << 23);
            Ks -= sh;
            a0 *= sc; a1 *= sc; a2 *= sc; a3 *= sc; a4 *= sc;
            a5 *= sc; a6 *= sc; a7 *= sc; a8 *= sc;
        };

        ushort4 gq[32];
        float   pbq[32];
        #pragma unroll
        for (int q = 0; q < 32; ++q) {
            gq[q]  = *(const ushort4*)(Gb + (((size_t)(1 + q)) << 8) + 4 * lane);
            pbq[q] = PBb[1 + q];
        }

        int t0 = 1;
        for (; t0 + 32 <= len; t0 += 32) {      // full groups: no per-step branch
            #pragma unroll
            for (int u = 0; u < 32; ++u) {
                const int t = t0 + u;
                const ushort4 gu = gq[u];
                const float pbf  = pbq[u];
                int tn = t + 32; if (tn > NT - 1) tn = NT - 1;
                gq[u]  = *(const ushort4*)(Gb + (((size_t)tn) << 8) + 4 * lane);
                pbq[u] = PBb[tn];
                ctc_step(gu, pbf);
                if ((u & 3) == 3) ctc_rescale();
            }
        }
        {   // remainder (< 32 steps), consume-only
            #pragma unroll
            for (int u = 0; u < 32; ++u) {
                if (t0 + u < len) ctc_step(gq[u], pbq[u]);
                if ((u & 3) == 3) ctc_rescale();
            }
        }

        smf[lane * 8 + 0] = a0; smf[lane * 8 + 1] = a1;
        smf[lane * 8 + 2] = a2; smf[lane * 8 + 3] = a3;
        smf[lane * 8 + 4] = a4; smf[lane * 8 + 5] = a5;
        smf[lane * 8 + 6] = a6; smf[lane * 8 + 7] = a7;
        if (lane == 63) smf[512] = a8;
        __syncthreads();
        if (lane == 0) {
            const int l = 2 * tl + 1;
            const float fsum = smf[l - 1] + smf[l - 2];
            if (fsum > 0.f) {
                const double s = (double)smf[l - 1] + (double)smf[l - 2];
                const double ll = (double)Ks * 0.6931471805599453 + log(s);
                ctc_out[b] = (float)(-ll / (double)tl);
                flags[b] = 0;
            } else {
                flags[b] = 1;       // k_dp_fix redoes this batch in fp64
            }
        }
    } else {
        // ------------- SoftDTW, hard-min wavefront, bf16 costs -------------
        const int b = bid - NB;
        const unsigned short* Db = Ddiag + (size_t)b * NDG * NS;

        float rp10 = BIGV, rp11 = BIGV, rp12 = BIGV, rp13 = BIGV;
        float rp20 = BIGV, rp21 = BIGV, rp22 = BIGV, rp23 = BIGV;
        if (lane == 0) rp10 = bf2f(Db[0]);

        ushort4 dq[32];
        #pragma unroll
        for (int q = 0; q < 32; ++q)
            dq[q] = *(const ushort4*)(Db + (size_t)(1 + q) * NS + 4 * lane);

        float res = 0.f;
        for (int d0 = 1; d0 < 1279; d0 += 32) {
            #pragma unroll
            for (int u = 0; u < 32; ++u) {
                const int d = d0 + u;
                const ushort4 Dv = dq[u];
                int dn = d + 32; if (dn > NDG - 1) dn = NDG - 1;
                dq[u] = *(const ushort4*)(Db + (size_t)dn * NS + 4 * lane);

                const float Dx = bf2f(Dv.x), Dy = bf2f(Dv.y);
                const float Dz = bf2f(Dv.z), Dw = bf2f(Dv.w);

                const float lf1 = dpp_shr1_f32(rp13, BIGV);
                const float lf2 = dpp_shr1_f32(rp23, BIGV);

                const float c0 = Dx + fminf(fminf(rp10, lf1),  lf2);
                const float c1 = Dy + fminf(fminf(rp11, rp10), rp20);
                const float c2 = Dz + fminf(fminf(rp12, rp11), rp21);
                const float c3 = Dw + fminf(fminf(rp13, rp12), rp22);

                rp20 = rp10; rp21 = rp11; rp22 = rp12; rp23 = rp13;
                rp10 = c0;   rp11 = c1;   rp12 = c2;   rp13 = c3;

                res = (d == NDG - 1) ? c3 : res;
            }
        }
        if (lane == 63) sdtw_out[b] = res;
    }
}

// ---------------------------------------------------------------------------
// K2b: fp64 CTC fallback for flagged batches (round-0/1/2-verified step and
// rescale code, depth-16 queue). Clean flags => immediate exit (~3 us).
// ---------------------------------------------------------------------------
__global__ __launch_bounds__(64, 1) void k_dp_fix(
    const float* __restrict__ lp, const int* __restrict__ tgt,
    const int* __restrict__ ilen, const int* __restrict__ tlen,
    const unsigned short* __restrict__ Gbf, const float* __restrict__ PB,
    float* __restrict__ ctc_out, const int* __restrict__ flags)
{
    __shared__ double smd[513];
    const int b = blockIdx.x;
    if (flags[b] == 0) return;
    const int lane = threadIdx.x;

    const int len = ilen[b];
    const int tl  = tlen[b];
    const float* lpb = lp + (size_t)b * NT * NV;
    const unsigned short* Gb = Gbf + ((size_t)(b * NT) << 8);
    const float* PBb = PB + b * NT;

    const int4 t4 = ((const int4*)(tgt + b * NS))[lane];
    const int prevw = __shfl_up(t4.w, 1);
    const double m1d = ((lane > 0) && (t4.x != prevw)) ? 1.0 : 0.0;
    const double m3d = (t4.y != t4.x) ? 1.0 : 0.0;
    const double m5d = (t4.z != t4.y) ? 1.0 : 0.0;
    const double m7d = (t4.w != t4.z) ? 1.0 : 0.0;

    double a0 = 0.0, a1 = 0.0, a2 = 0.0, a3 = 0.0, a4 = 0.0,
           a5 = 0.0, a6 = 0.0, a7 = 0.0, a8 = 0.0;
    if (lane == 0) {
        a0 = (double)__expf(lpb[0]);
        a1 = (double)__expf(lpb[t4.x]);
    }
    long long Ksum = 0;

    auto ctc_step = [&](const ushort4 gu, const float pbf) {
        const double pb = (double)pbf;
        const double p0 = (double)bf2f(gu.x), p1 = (double)bf2f(gu.y);
        const double p2 = (double)bf2f(gu.z), p3 = (double)bf2f(gu.w);
        const double l7 = dpp_shr1_zero_f64(a7);
        const double n0 = (a0 + l7) * pb;
        const double n1 = fma(m1d, l7, a1 + a0) * p0;
        const double n2 = (a2 + a1) * pb;
        const double n3 = fma(m3d, a1, a3 + a2) * p1;
        const double n4 = (a4 + a3) * pb;
        const double n5 = fma(m5d, a3, a5 + a4) * p2;
        const double n6 = (a6 + a5) * pb;
        const double n7 = fma(m7d, a5, a7 + a6) * p3;
        const double n8 = (a8 + a7) * pb;
        a0 = n0; a1 = n1; a2 = n2; a3 = n3; a4 = n4;
        a5 = n5; a6 = n6; a7 = n7; a8 = n8;
    };
    auto ctc_rescale = [&]() {
        double m = fmax(a0, a1);
        m = fmax(m, a2); m = fmax(m, a3); m = fmax(m, a4);
        m = fmax(m, a5); m = fmax(m, a6); m = fmax(m, a7);
        m = fmax(m, a8);
        int Eb = (__double2hiint(m) >> 20) & 0x7ff;
        int Ex = wave_imax_dpp(Eb);
        if (Ex < 1) Ex = 1;
        const double inv = __hiloint2double((2046 - Ex) << 20, 0); // 2^(1023-Ex)
        Ksum += (long long)(Ex - 1023);
        a0 *= inv; a1 *= inv; a2 *= inv; a3 *= inv; a4 *= inv;
        a5 *= inv; a6 *= inv; a7 *= inv; a8 *= inv;
    };

    ushort4 gq[16];
    float   pbq[16];
    #pragma unroll
    for (int q = 0; q < 16; ++q) {
        gq[q]  = *(const ushort4*)(Gb + (((size_t)(1 + q)) << 8) + 4 * lane);
        pbq[q] = PBb[1 + q];
    }

    int t0 = 1;
    for (; t0 + 16 <= len; t0 += 16) {      // full groups: no per-step branch
        #pragma unroll
        for (int u = 0; u < 16; ++u) {
            const int t = t0 + u;
            const ushort4 gu = gq[u];
            const float pbf  = pbq[u];
            int tn = t + 16; if (tn > NT - 1) tn = NT - 1;
            gq[u]  = *(const ushort4*)(Gb + (((size_t)tn) << 8) + 4 * lane);
            pbq[u] = PBb[tn];
            ctc_step(gu, pbf);
            if (u == 7 || u == 15) ctc_rescale();
        }
    }
    {   // remainder (< 16 steps), consume-only
        #pragma unroll
        for (int u = 0; u < 16; ++u) {
            if (t0 + u < len) ctc_step(gq[u], pbq[u]);
            if (u == 7) ctc_rescale();
        }
    }

    smd[lane * 8 + 0] = a0; smd[lane * 8 + 1] = a1;
    smd[lane * 8 + 2] = a2; smd[lane * 8 + 3] = a3;
    smd[lane * 8 + 4] = a4; smd[lane * 8 + 5] = a5;
    smd[lane * 8 + 6] = a6; smd[lane * 8 + 7] = a7;
    if (lane == 63) smd[512] = a8;
    __syncthreads();
    if (lane == 0) {
        const int l = 2 * tl + 1;
        const double s = smd[l - 1] + smd[l - 2];
        const double ll = (double)Ksum * 0.6931471805599453 + log(s);
        ctc_out[b] = (float)(-ll / (double)tl);
    }
}

// ---------------------------------------------------------------------------
// K3: final scalar = mean(ctc) + mean(sdtw)
// ---------------------------------------------------------------------------
__global__ __launch_bounds__(64) void k_final(
    const float* __restrict__ ctc_out, const float* __restrict__ sdtw_out,
    float* __restrict__ out)
{
    int lane = threadIdx.x;
    float c = ctc_out[lane];
    float s = sdtw_out[lane];
    #pragma unroll
    for (int off = 32; off > 0; off >>= 1) {
        c += __shfl_down(c, off);
        s += __shfl_down(s, off);
    }
    if (lane == 0) out[0] = c / 64.f + s / 64.f;
}

extern "C" void kernel_launch(void* const* d_in, const int* in_sizes, int n_in,
                              void* d_out, int out_size, void* d_ws, size_t ws_size,
                              hipStream_t stream) {
    const float* lp   = (const float*)d_in[0];
    const float* fm   = (const float*)d_in[1];
    const int*   tgt  = (const int*)d_in[2];
    const int*   ilen = (const int*)d_in[3];
    const int*   tlen = (const int*)d_in[4];
    float* out = (float*)d_out;

    // ws: Ddiag bf16 (41.9 MB) | Gbf bf16 (32 MB) | PB (256 KB) | res | flags
    char* ws = (char*)d_ws;
    unsigned short* Ddiag = (unsigned short*)ws;
    size_t dbytes = (size_t)NB * NDG * NS * sizeof(unsigned short); // 41,910,272
    unsigned short* Gbf = (unsigned short*)(ws + dbytes);
    size_t gbytes = (size_t)NB * NT * NS * sizeof(unsigned short);  // 33,554,432
    float* PB = (float*)(ws + dbytes + gbytes);
    size_t pbytes = (size_t)NB * NT * sizeof(float);                // 262,144
    float* ctc_res  = (float*)(ws + dbytes + gbytes + pbytes);
    float* sdtw_res = ctc_res + 64;
    int*   flags    = (int*)(sdtw_res + 64);

    hipLaunchKernelGGL(k_dmat, dim3(NB * 8), dim3(512), 0, stream,
                       lp, fm, tgt, Ddiag, Gbf, PB);
    hipLaunchKernelGGL(k_dp, dim3(2 * NB), dim3(64), 0, stream,
                       lp, tgt, ilen, tlen, Ddiag, Gbf, PB, ctc_res, sdtw_res, flags);
    hipLaunchKernelGGL(k_dp_fix, dim3(NB), dim3(64), 0, stream,
                       lp, tgt, ilen, tlen, Gbf, PB, ctc_res, flags);
    hipLaunchKernelGGL(k_final, dim3(1), dim3(64), 0, stream, ctc_res, sdtw_res, out);
}

// Round 9
// 286.366 us; speedup vs baseline: 1.0911x; 1.0911x over previous
//
#include <hip/hip_runtime.h>
#include <math.h>

// Problem constants (fixed by setup_inputs)
constexpr int NB = 64;     // batch
constexpr int NT = 1024;   // time steps
constexpr int NV = 256;    // vocab
constexpr int NS = 256;    // target length (padded)
constexpr int NL = 2 * NS + 1;        // 513 extended CTC states
constexpr int NDG = NT + NS - 1;      // 1279 anti-diagonals
__device__ constexpr float BIGV = 1e10f;

using f32x4 = __attribute__((ext_vector_type(4))) float;
using s16x8 = __attribute__((ext_vector_type(8))) short;

// ---------------- DPP cross-lane helpers ----------------
__device__ __forceinline__ float dpp_shr1_f32(float x, float lane0val) {
    int r = __builtin_amdgcn_update_dpp(__float_as_int(lane0val),
                                        __float_as_int(x), 0x138, 0xf, 0xf, false);
    return __int_as_float(r);
}
__device__ __forceinline__ double dpp_shr1_zero_f64(double x) {
    union { double d; unsigned long long u; } c; c.d = x;
    int lo = (int)(c.u & 0xffffffffull), hi = (int)(c.u >> 32);
    int nlo = __builtin_amdgcn_update_dpp(0, lo, 0x138, 0xf, 0xf, true);
    int nhi = __builtin_amdgcn_update_dpp(0, hi, 0x138, 0xf, 0xf, true);
    c.u = ((unsigned long long)(unsigned)nhi << 32) | (unsigned)nlo;
    return c.d;
}
__device__ __forceinline__ int wave_imax_dpp(int x) {   // non-negative x
    int t;
    t = __builtin_amdgcn_update_dpp(0, x, 0x111, 0xf, 0xf, true); x = max(x, t);
    t = __builtin_amdgcn_update_dpp(0, x, 0x112, 0xf, 0xf, true); x = max(x, t);
    t = __builtin_amdgcn_update_dpp(0, x, 0x114, 0xf, 0xf, true); x = max(x, t);
    t = __builtin_amdgcn_update_dpp(0, x, 0x118, 0xf, 0xf, true); x = max(x, t);
    t = __builtin_amdgcn_update_dpp(0, x, 0x142, 0xf, 0xf, true); x = max(x, t);
    t = __builtin_amdgcn_update_dpp(0, x, 0x143, 0xf, 0xf, true); x = max(x, t);
    return __builtin_amdgcn_readlane(x, 63);
}
__device__ __forceinline__ float row16_sum(float x) {
    x += __int_as_float(__builtin_amdgcn_update_dpp(0, __float_as_int(x), 0x111, 0xf, 0xf, true));
    x += __int_as_float(__builtin_amdgcn_update_dpp(0, __float_as_int(x), 0x112, 0xf, 0xf, true));
    x += __int_as_float(__builtin_amdgcn_update_dpp(0, __float_as_int(x), 0x114, 0xf, 0xf, true));
    x += __int_as_float(__builtin_amdgcn_update_dpp(0, __float_as_int(x), 0x118, 0xf, 0xf, true));
    return x;
}
__device__ __forceinline__ unsigned short f2bf(float x) {   // round-to-nearest-even
    unsigned u = __float_as_uint(x);
    return (unsigned short)((u + 0x7fffu + ((u >> 16) & 1u)) >> 16);
}
__device__ __forceinline__ float bf2f(unsigned short h) {
    return __uint_as_float((unsigned)h << 16);
}

// ---------------------------------------------------------------------------
// K_MAIN (heterogeneous, 576 blocks x 512 threads):
//   blocks 0..63   : CTC fp64 (R0-verified recurrence/rescale), reading lp
//                    DIRECTLY (5 dword loads + 5 expf per step, depth-8
//                    queue) — no Gbf/PB dependency, so it runs CONCURRENTLY
//                    with the dmat blocks. Dispatched first so these 64
//                    blocks grab CUs before the 512 dmat blocks.
//   blocks 64..575 : dmat (identical to verified version, minus the Gbf
//                    gather and PB store, which no longer exist).
// fp32-CTC was abandoned: measured (R8 k_dp_fix FETCH=5.4MB ~ 10 batches)
// cross-state dynamic range exceeds fp32's ~250-bit window; the fp64
// fallback serialized a full pass, erasing the gain.
// ---------------------------------------------------------------------------
__global__ __launch_bounds__(512, 1) void k_main(
    const float* __restrict__ lp, const float* __restrict__ fm,
    const int* __restrict__ tgt, const int* __restrict__ ilen,
    const int* __restrict__ tlen, unsigned short* __restrict__ Ddiag,
    float* __restrict__ ctc_out)
{
    constexpr int ESTR = 264;
    constexpr int FSTR = 264;
    constexpr int TSTR = 40;
    constexpr int PSTR = 40;
    constexpr int DSTR = 130;

    __shared__ __align__(16) unsigned char uni[128 * ESTR * 2];  // E / Dst / smd
    __shared__ __align__(16) unsigned short FT[32 * FSTR];
    __shared__ __align__(16) unsigned short tgf[256 * TSTR];
    __shared__ __align__(16) unsigned short pb16[128 * PSTR];
    __shared__ float tsq[256];
    __shared__ float psq[128];

    if (blockIdx.x < NB) {
        // ======================= CTC (one wave) =======================
        if (threadIdx.x >= 64) return;
        const int lane = threadIdx.x;
        const int b = blockIdx.x;
        const int len = ilen[b];          // wave-uniform (768..1024)
        const int tl  = tlen[b];
        const float* lpb = lp + (size_t)b * NT * NV;

        const int4 t4 = ((const int4*)(tgt + b * NS))[lane];
        const int prevw = __shfl_up(t4.w, 1);
        const double m1d = ((lane > 0) && (t4.x != prevw)) ? 1.0 : 0.0;
        const double m3d = (t4.y != t4.x) ? 1.0 : 0.0;
        const double m5d = (t4.z != t4.y) ? 1.0 : 0.0;
        const double m7d = (t4.w != t4.z) ? 1.0 : 0.0;

        double a0 = 0.0, a1 = 0.0, a2 = 0.0, a3 = 0.0, a4 = 0.0,
               a5 = 0.0, a6 = 0.0, a7 = 0.0, a8 = 0.0;
        if (lane == 0) {
            a0 = (double)__expf(lpb[0]);
            a1 = (double)__expf(lpb[t4.x]);
        }
        long long Ksum = 0;

        auto ctc_step = [&](float f0, float f1, float f2, float f3, float fb) {
            const double pb = (double)__expf(fb);
            const double p0 = (double)__expf(f0), p1 = (double)__expf(f1);
            const double p2 = (double)__expf(f2), p3 = (double)__expf(f3);
            const double l7 = dpp_shr1_zero_f64(a7);
            const double n0 = (a0 + l7) * pb;
            const double n1 = fma(m1d, l7, a1 + a0) * p0;
            const double n2 = (a2 + a1) * pb;
            const double n3 = fma(m3d, a1, a3 + a2) * p1;
            const double n4 = (a4 + a3) * pb;
            const double n5 = fma(m5d, a3, a5 + a4) * p2;
            const double n6 = (a6 + a5) * pb;
            const double n7 = fma(m7d, a5, a7 + a6) * p3;
            const double n8 = (a8 + a7) * pb;
            a0 = n0; a1 = n1; a2 = n2; a3 = n3; a4 = n4;
            a5 = n5; a6 = n6; a7 = n7; a8 = n8;
        };
        auto ctc_rescale = [&]() {
            double m = fmax(a0, a1);
            m = fmax(m, a2); m = fmax(m, a3); m = fmax(m, a4);
            m = fmax(m, a5); m = fmax(m, a6); m = fmax(m, a7);
            m = fmax(m, a8);
            int Eb = (__double2hiint(m) >> 20) & 0x7ff;
            int Ex = wave_imax_dpp(Eb);
            if (Ex < 1) Ex = 1;
            const double inv = __hiloint2double((2046 - Ex) << 20, 0); // 2^(1023-Ex)
            Ksum += (long long)(Ex - 1023);
            a0 *= inv; a1 *= inv; a2 *= inv; a3 *= inv; a4 *= inv;
            a5 *= inv; a6 *= inv; a7 *= inv; a8 *= inv;
        };

        // depth-8 queue of raw log-probs: 4 label dwords + blank per step
        float q0[8], q1[8], q2[8], q3[8], qb[8];
        #pragma unroll
        for (int u = 0; u < 8; ++u) {
            const float* r = lpb + (size_t)(1 + u) * NV;
            q0[u] = r[t4.x]; q1[u] = r[t4.y];
            q2[u] = r[t4.z]; q3[u] = r[t4.w];
            qb[u] = r[0];
        }

        int t0 = 1;
        for (; t0 + 8 <= len; t0 += 8) {    // full groups: straight-line
            #pragma unroll
            for (int u = 0; u < 8; ++u) {
                const float f0 = q0[u], f1 = q1[u], f2 = q2[u], f3 = q3[u];
                const float fb = qb[u];
                int tn = t0 + 8 + u; if (tn > NT - 1) tn = NT - 1;
                const float* r = lpb + (size_t)tn * NV;
                q0[u] = r[t4.x]; q1[u] = r[t4.y];
                q2[u] = r[t4.z]; q3[u] = r[t4.w];
                qb[u] = r[0];
                ctc_step(f0, f1, f2, f3, fb);
                if (u == 7) ctc_rescale();
            }
        }
        {   // remainder (< 8 steps), consume-only; <=7 unrescaled steps is
            // trivially inside fp64 range
            #pragma unroll
            for (int u = 0; u < 8; ++u) {
                if (t0 + u < len) ctc_step(q0[u], q1[u], q2[u], q3[u], qb[u]);
            }
        }

        // single-wave readout through LDS (lockstep: no barrier needed)
        double* smd = (double*)uni;
        smd[lane * 8 + 0] = a0; smd[lane * 8 + 1] = a1;
        smd[lane * 8 + 2] = a2; smd[lane * 8 + 3] = a3;
        smd[lane * 8 + 4] = a4; smd[lane * 8 + 5] = a5;
        smd[lane * 8 + 6] = a6; smd[lane * 8 + 7] = a7;
        if (lane == 63) smd[512] = a8;
        if (lane == 0) {
            const int l = 2 * tl + 1;
            const double s = smd[l - 1] + smd[l - 2];
            const double ll = (double)Ksum * 0.6931471805599453 + log(s);
            ctc_out[b] = (float)(-ll / (double)tl);
        }
        return;
    }

    // ========================== dmat (8 waves) ==========================
    unsigned short* E = (unsigned short*)uni;
    float* Dst = (float*)uni;

    const int tid  = threadIdx.x;
    const int lane = tid & 63;
    const int w    = tid >> 6;          // 0..7
    const int bb   = blockIdx.x - NB;
    const int b    = bb >> 3;
    const int a0   = (bb & 7) * 128;

    const int row2 = tid >> 1;          // 0..255 (vocab / target row)
    const int half = tid & 1;           // 0/1: cols 0..11 / 12..23
    const int k0   = half * 12;

    {   // FT: vocab feature matrix, bf16, transposed [k][v]
        const float* fr = fm + row2 * 24 + k0;
        #pragma unroll
        for (int k = 0; k < 12; k += 4) {
            float4 t4 = *(const float4*)(fr + k);
            FT[(k0 + k + 0) * FSTR + row2] = f2bf(t4.x);
            FT[(k0 + k + 1) * FSTR + row2] = f2bf(t4.y);
            FT[(k0 + k + 2) * FSTR + row2] = f2bf(t4.z);
            FT[(k0 + k + 3) * FSTR + row2] = f2bf(t4.w);
        }
        if (half) {
            #pragma unroll
            for (int n = 24; n < 32; ++n) FT[n * FSTR + row2] = 0;
        }
    }
    {   // tgf: target feature rows, bf16, row-major; tsq: their square sums
        const int lab_r = tgt[b * NS + row2];
        const float* fr = fm + lab_r * 24 + k0;
        float s = 0.f;
        #pragma unroll
        for (int k = 0; k < 12; k += 4) {
            float4 t4 = *(const float4*)(fr + k);
            unsigned p0 = f2bf(t4.x) | ((unsigned)f2bf(t4.y) << 16);
            unsigned p1 = f2bf(t4.z) | ((unsigned)f2bf(t4.w) << 16);
            *(unsigned*)&tgf[row2 * TSTR + k0 + k]     = p0;
            *(unsigned*)&tgf[row2 * TSTR + k0 + k + 2] = p1;
            s += t4.x * t4.x + t4.y * t4.y + t4.z * t4.z + t4.w * t4.w;
        }
        const float sf = s + __shfl_xor(s, 1);
        if (!half) tsq[row2] = sf;
        else {
            #pragma unroll
            for (int k = 24; k < 32; k += 2) *(unsigned*)&tgf[row2 * TSTR + k] = 0;
        }
    }
    {   // E: exp(log_probs) for 128 time rows, bf16
        const float* src = lp + ((size_t)b * NT + a0) * NV;
        #pragma unroll
        for (int it = 0; it < 16; ++it) {
            int f4  = it * 512 + tid;
            int row = f4 >> 6;
            int c4  = f4 & 63;
            float4 v = *(const float4*)(src + row * NV + c4 * 4);
            float e0 = __expf(v.x), e1 = __expf(v.y);
            float e2 = __expf(v.z), e3 = __expf(v.w);
            unsigned* dst = (unsigned*)&E[row * ESTR + c4 * 4];
            dst[0] = f2bf(e0) | ((unsigned)f2bf(e1) << 16);
            dst[1] = f2bf(e2) | ((unsigned)f2bf(e3) << 16);
        }
    }
    __syncthreads();

    // ---- MFMA-1: P = E(128x256) * FT^T(256x32)  (only 24 cols real) ----
    const int m0  = 16 * w;           // 16 rows per wave
    const int q   = lane >> 4;
    const int n16 = lane & 15;
    f32x4 acc00 = {0.f, 0.f, 0.f, 0.f}, acc01 = acc00;
    #pragma unroll
    for (int ks = 0; ks < 8; ++ks) {
        s16x8 a0f = *(const s16x8*)&E[(m0 + n16) * ESTR + ks * 32 + q * 8];
        s16x8 b0f = *(const s16x8*)&FT[(n16) * FSTR + ks * 32 + q * 8];
        s16x8 b1f = *(const s16x8*)&FT[(16 + n16) * FSTR + ks * 32 + q * 8];
        acc00 = __builtin_amdgcn_mfma_f32_16x16x32_bf16(a0f, b0f, acc00, 0, 0, 0);
        acc01 = __builtin_amdgcn_mfma_f32_16x16x32_bf16(a0f, b1f, acc01, 0, 0, 0);
    }
    #pragma unroll
    for (int r = 0; r < 4; ++r) {
        float s0 = acc00[r] * acc00[r] + acc01[r] * acc01[r];
        s0 = row16_sum(s0);
        if (n16 == 15) psq[m0 + 4 * q + r] = s0;
        pb16[(m0 + 4 * q + r) * PSTR + n16]      = f2bf(acc00[r]);
        pb16[(m0 + 4 * q + r) * PSTR + 16 + n16] = f2bf(acc01[r]);
    }

    // ---- per h: Dst = |P|^2 + |T|^2 - 2 P T^T, then diagonal extraction ----
    #pragma unroll 1
    for (int h = 0; h < 2; ++h) {
        __syncthreads();
        s16x8 pa0 = *(const s16x8*)&pb16[(m0 + n16) * PSTR + q * 8];
        float ps0[4];
        #pragma unroll
        for (int r = 0; r < 4; ++r) ps0[r] = psq[m0 + 4 * q + r];
        #pragma unroll
        for (int nt = 0; nt < 8; ++nt) {
            const int j0 = 16 * nt;
            s16x8 tb = *(const s16x8*)&tgf[(128 * h + j0 + n16) * TSTR + q * 8];
            float tq = tsq[128 * h + j0 + n16];
            f32x4 z = {0.f, 0.f, 0.f, 0.f};
            f32x4 d0 = __builtin_amdgcn_mfma_f32_16x16x32_bf16(pa0, tb, z, 0, 0, 0);
            #pragma unroll
            for (int r = 0; r < 4; ++r)
                Dst[(m0 + 4 * q + r) * DSTR + j0 + n16] = ps0[r] + tq - 2.f * d0[r];
        }
        __syncthreads();
        // anti-diagonal extraction; dp = 8*i + w covers 0..255
        const size_t dbase = ((size_t)b * NDG + a0 + 128 * h) * NS + 128 * h;
        #pragma unroll 4
        for (int i = 0; i < 32; ++i) {
            int dp  = 8 * i + w;
            int jlo = dp > 127 ? dp - 127 : 0;
            int jhi = dp < 127 ? dp : 127;
            #pragma unroll
            for (int c = 0; c < 2; ++c) {
                int jj = jlo + 64 * c + lane;
                if (jj <= jhi) {
                    unsigned short vv = f2bf(Dst[(dp - jj) * DSTR + jj]);
                    Ddiag[dbase + (size_t)dp * NS + jj] = vv;
                }
            }
        }
    }
}

// ---------------------------------------------------------------------------
// K_SDTW: hard-min wavefront on bf16 anti-diagonals (verified, unchanged).
// ---------------------------------------------------------------------------
__global__ __launch_bounds__(64, 1) void k_sdtw(
    const unsigned short* __restrict__ Ddiag, float* __restrict__ sdtw_out)
{
    const int lane = threadIdx.x;
    const int b = blockIdx.x;
    const unsigned short* Db = Ddiag + (size_t)b * NDG * NS;

    float rp10 = BIGV, rp11 = BIGV, rp12 = BIGV, rp13 = BIGV;
    float rp20 = BIGV, rp21 = BIGV, rp22 = BIGV, rp23 = BIGV;
    if (lane == 0) rp10 = bf2f(Db[0]);

    ushort4 dq[32];
    #pragma unroll
    for (int q = 0; q < 32; ++q)
        dq[q] = *(const ushort4*)(Db + (size_t)(1 + q) * NS + 4 * lane);

    float res = 0.f;
    for (int d0 = 1; d0 < 1279; d0 += 32) {
        #pragma unroll
        for (int u = 0; u < 32; ++u) {
            const int d = d0 + u;
            const ushort4 Dv = dq[u];
            int dn = d + 32; if (dn > NDG - 1) dn = NDG - 1;
            dq[u] = *(const ushort4*)(Db + (size_t)dn * NS + 4 * lane);

            const float Dx = bf2f(Dv.x), Dy = bf2f(Dv.y);
            const float Dz = bf2f(Dv.z), Dw = bf2f(Dv.w);

            const float lf1 = dpp_shr1_f32(rp13, BIGV);
            const float lf2 = dpp_shr1_f32(rp23, BIGV);

            const float c0 = Dx + fminf(fminf(rp10, lf1),  lf2);
            const float c1 = Dy + fminf(fminf(rp11, rp10), rp20);
            const float c2 = Dz + fminf(fminf(rp12, rp11), rp21);
            const float c3 = Dw + fminf(fminf(rp13, rp12), rp22);

            rp20 = rp10; rp21 = rp11; rp22 = rp12; rp23 = rp13;
            rp10 = c0;   rp11 = c1;   rp12 = c2;   rp13 = c3;

            res = (d == NDG - 1) ? c3 : res;
        }
    }
    if (lane == 63) sdtw_out[b] = res;
}

// ---------------------------------------------------------------------------
// K3: final scalar = mean(ctc) + mean(sdtw)
// ---------------------------------------------------------------------------
__global__ __launch_bounds__(64) void k_final(
    const float* __restrict__ ctc_out, const float* __restrict__ sdtw_out,
    float* __restrict__ out)
{
    int lane = threadIdx.x;
    float c = ctc_out[lane];
    float s = sdtw_out[lane];
    #pragma unroll
    for (int off = 32; off > 0; off >>= 1) {
        c += __shfl_down(c, off);
        s += __shfl_down(s, off);
    }
    if (lane == 0) out[0] = c / 64.f + s / 64.f;
}

extern "C" void kernel_launch(void* const* d_in, const int* in_sizes, int n_in,
                              void* d_out, int out_size, void* d_ws, size_t ws_size,
                              hipStream_t stream) {
    const float* lp   = (const float*)d_in[0];
    const float* fm   = (const float*)d_in[1];
    const int*   tgt  = (const int*)d_in[2];
    const int*   ilen = (const int*)d_in[3];
    const int*   tlen = (const int*)d_in[4];
    float* out = (float*)d_out;

    // ws layout: Ddiag bf16 (41.9 MB) | ctc_res | sdtw_res
    char* ws = (char*)d_ws;
    unsigned short* Ddiag = (unsigned short*)ws;
    size_t dbytes = (size_t)NB * NDG * NS * sizeof(unsigned short); // 41,910,272
    float* ctc_res  = (float*)(ws + dbytes);
    float* sdtw_res = ctc_res + 64;

    hipLaunchKernelGGL(k_main, dim3(NB + NB * 8), dim3(512), 0, stream,
                       lp, fm, tgt, ilen, tlen, Ddiag, ctc_res);
    hipLaunchKernelGGL(k_sdtw, dim3(NB), dim3(64), 0, stream,
                       Ddiag, sdtw_res);
    hipLaunchKernelGGL(k_final, dim3(1), dim3(64), 0, stream, ctc_res, sdtw_res, out);
}

// Round 10
// 225.312 us; speedup vs baseline: 1.3868x; 1.2710x over previous
//
#include <hip/hip_runtime.h>
#include <math.h>

// Problem constants (fixed by setup_inputs)
constexpr int NB = 64;     // batch
constexpr int NT = 1024;   // time steps
constexpr int NV = 256;    // vocab
constexpr int NS = 256;    // target length (padded)
constexpr int NL = 2 * NS + 1;        // 513 extended CTC states
constexpr int NDG = NT + NS - 1;      // 1279 anti-diagonals
__device__ constexpr float BIGV = 1e10f;

using f32x4 = __attribute__((ext_vector_type(4))) float;
using s16x8 = __attribute__((ext_vector_type(8))) short;

// ---------------- DPP cross-lane helpers ----------------
__device__ __forceinline__ float dpp_shr1_f32(float x, float lane0val) {
    int r = __builtin_amdgcn_update_dpp(__float_as_int(lane0val),
                                        __float_as_int(x), 0x138, 0xf, 0xf, false);
    return __int_as_float(r);
}
__device__ __forceinline__ double dpp_shr1_zero_f64(double x) {
    union { double d; unsigned long long u; } c; c.d = x;
    int lo = (int)(c.u & 0xffffffffull), hi = (int)(c.u >> 32);
    int nlo = __builtin_amdgcn_update_dpp(0, lo, 0x138, 0xf, 0xf, true);
    int nhi = __builtin_amdgcn_update_dpp(0, hi, 0x138, 0xf, 0xf, true);
    c.u = ((unsigned long long)(unsigned)nhi << 32) | (unsigned)nlo;
    return c.d;
}
__device__ __forceinline__ int wave_imax_dpp(int x) {   // non-negative x
    int t;
    t = __builtin_amdgcn_update_dpp(0, x, 0x111, 0xf, 0xf, true); x = max(x, t);
    t = __builtin_amdgcn_update_dpp(0, x, 0x112, 0xf, 0xf, true); x = max(x, t);
    t = __builtin_amdgcn_update_dpp(0, x, 0x114, 0xf, 0xf, true); x = max(x, t);
    t = __builtin_amdgcn_update_dpp(0, x, 0x118, 0xf, 0xf, true); x = max(x, t);
    t = __builtin_amdgcn_update_dpp(0, x, 0x142, 0xf, 0xf, true); x = max(x, t);
    t = __builtin_amdgcn_update_dpp(0, x, 0x143, 0xf, 0xf, true); x = max(x, t);
    return __builtin_amdgcn_readlane(x, 63);
}
__device__ __forceinline__ float row16_sum(float x) {
    x += __int_as_float(__builtin_amdgcn_update_dpp(0, __float_as_int(x), 0x111, 0xf, 0xf, true));
    x += __int_as_float(__builtin_amdgcn_update_dpp(0, __float_as_int(x), 0x112, 0xf, 0xf, true));
    x += __int_as_float(__builtin_amdgcn_update_dpp(0, __float_as_int(x), 0x114, 0xf, 0xf, true));
    x += __int_as_float(__builtin_amdgcn_update_dpp(0, __float_as_int(x), 0x118, 0xf, 0xf, true));
    return x;
}
__device__ __forceinline__ unsigned short f2bf(float x) {   // round-to-nearest-even
    unsigned u = __float_as_uint(x);
    return (unsigned short)((u + 0x7fffu + ((u >> 16) & 1u)) >> 16);
}
__device__ __forceinline__ float bf2f(unsigned short h) {
    return __uint_as_float((unsigned)h << 16);
}

// ---------------------------------------------------------------------------
// K1 (MFMA): 64-row tile per block, 256 threads (4 waves), 1024 blocks.
// LDS = 77.6 KB -> 2 blocks/CU: during one block's barrier drain the
// co-resident block keeps issuing (cross-block phase overlap). Same total
// work / dispatch rounds as the 128-row version; double the TLP.
// ---------------------------------------------------------------------------
__global__ __launch_bounds__(256, 2) void k_dmat(
    const float* __restrict__ lp, const float* __restrict__ fm,
    const int* __restrict__ tgt, unsigned short* __restrict__ Ddiag,
    unsigned short* __restrict__ Gbf, float* __restrict__ PB)
{
    constexpr int ESTR = 264;
    constexpr int FSTR = 264;
    constexpr int TSTR = 40;
    constexpr int PSTR = 40;
    constexpr int DSTR = 130;
    constexpr int RT   = 64;            // rows per tile

    __shared__ __align__(16) unsigned char uni[RT * ESTR * 2];   // E / Dst union
    __shared__ __align__(16) unsigned short FT[32 * FSTR];
    __shared__ __align__(16) unsigned short tgf[256 * TSTR];
    __shared__ __align__(16) unsigned short pb16[RT * PSTR];
    __shared__ float tsq[256];
    __shared__ float psq[RT];

    unsigned short* E = (unsigned short*)uni;
    float* Dst = (float*)uni;

    const int tid  = threadIdx.x;
    const int lane = tid & 63;
    const int w    = tid >> 6;          // 0..3
    const int b    = blockIdx.x >> 4;
    const int a0   = (blockIdx.x & 15) * RT;

    {   // FT: vocab feature matrix, bf16, transposed [k][v]
        const float* fr = fm + tid * 24;
        #pragma unroll
        for (int k = 0; k < 24; k += 4) {
            float4 t4 = *(const float4*)(fr + k);
            FT[(k + 0) * FSTR + tid] = f2bf(t4.x);
            FT[(k + 1) * FSTR + tid] = f2bf(t4.y);
            FT[(k + 2) * FSTR + tid] = f2bf(t4.z);
            FT[(k + 3) * FSTR + tid] = f2bf(t4.w);
        }
        #pragma unroll
        for (int n = 24; n < 32; ++n) FT[n * FSTR + tid] = 0;
    }
    const int lab = tgt[b * NS + tid];
    {   // tgf: target feature rows, bf16, row-major; tsq: square sums
        const float* fr = fm + lab * 24;
        float s = 0.f;
        #pragma unroll
        for (int k = 0; k < 24; k += 4) {
            float4 t4 = *(const float4*)(fr + k);
            unsigned p0 = f2bf(t4.x) | ((unsigned)f2bf(t4.y) << 16);
            unsigned p1 = f2bf(t4.z) | ((unsigned)f2bf(t4.w) << 16);
            *(unsigned*)&tgf[tid * TSTR + k]     = p0;
            *(unsigned*)&tgf[tid * TSTR + k + 2] = p1;
            s += t4.x * t4.x + t4.y * t4.y + t4.z * t4.z + t4.w * t4.w;
        }
        #pragma unroll
        for (int k = 24; k < 32; k += 2) *(unsigned*)&tgf[tid * TSTR + k] = 0;
        tsq[tid] = s;
    }
    {   // E: exp(log_probs) for 64 time rows, bf16
        const float* src = lp + ((size_t)b * NT + a0) * NV;
        #pragma unroll
        for (int it = 0; it < 16; ++it) {
            int f4  = it * 256 + tid;   // 0..4095 = 64 rows x 64 float4
            int row = f4 >> 6;
            int c4  = f4 & 63;
            float4 v = *(const float4*)(src + row * NV + c4 * 4);
            float e0 = __expf(v.x), e1 = __expf(v.y);
            float e2 = __expf(v.z), e3 = __expf(v.w);
            unsigned* dst = (unsigned*)&E[row * ESTR + c4 * 4];
            dst[0] = f2bf(e0) | ((unsigned)f2bf(e1) << 16);
            dst[1] = f2bf(e2) | ((unsigned)f2bf(e3) << 16);
            if (c4 == 0) PB[b * NT + a0 + row] = e0;
        }
    }
    __syncthreads();

    {   // Gbf gather: per time row, prob of each target label (bf16)
        unsigned short* gd = Gbf + (((size_t)(b * NT + a0)) << 8) + tid;
        #pragma unroll 8
        for (int r = 0; r < RT; ++r) gd[(size_t)r << 8] = E[r * ESTR + lab];
    }

    // ---- MFMA-1: P = E(64x256) * FT^T(256x32)  (only 24 cols real) ----
    const int m0  = 16 * w;           // 16 rows per wave
    const int q   = lane >> 4;
    const int n16 = lane & 15;
    f32x4 acc00 = {0.f, 0.f, 0.f, 0.f}, acc01 = acc00;
    #pragma unroll
    for (int ks = 0; ks < 8; ++ks) {
        s16x8 a0f = *(const s16x8*)&E[(m0 + n16) * ESTR + ks * 32 + q * 8];
        s16x8 b0f = *(const s16x8*)&FT[(n16) * FSTR + ks * 32 + q * 8];
        s16x8 b1f = *(const s16x8*)&FT[(16 + n16) * FSTR + ks * 32 + q * 8];
        acc00 = __builtin_amdgcn_mfma_f32_16x16x32_bf16(a0f, b0f, acc00, 0, 0, 0);
        acc01 = __builtin_amdgcn_mfma_f32_16x16x32_bf16(a0f, b1f, acc01, 0, 0, 0);
    }
    #pragma unroll
    for (int r = 0; r < 4; ++r) {
        float s0 = acc00[r] * acc00[r] + acc01[r] * acc01[r];
        s0 = row16_sum(s0);
        if (n16 == 15) psq[m0 + 4 * q + r] = s0;
        pb16[(m0 + 4 * q + r) * PSTR + n16]      = f2bf(acc00[r]);
        pb16[(m0 + 4 * q + r) * PSTR + 16 + n16] = f2bf(acc01[r]);
    }

    // ---- per h: Dst = |P|^2 + |T|^2 - 2 P T^T, then diagonal extraction ----
    #pragma unroll 1
    for (int h = 0; h < 2; ++h) {
        __syncthreads();
        s16x8 pa0 = *(const s16x8*)&pb16[(m0 + n16) * PSTR + q * 8];
        float ps0[4];
        #pragma unroll
        for (int r = 0; r < 4; ++r) ps0[r] = psq[m0 + 4 * q + r];
        #pragma unroll
        for (int nt = 0; nt < 8; ++nt) {
            const int j0 = 16 * nt;
            s16x8 tb = *(const s16x8*)&tgf[(128 * h + j0 + n16) * TSTR + q * 8];
            float tq = tsq[128 * h + j0 + n16];
            f32x4 z = {0.f, 0.f, 0.f, 0.f};
            f32x4 d0 = __builtin_amdgcn_mfma_f32_16x16x32_bf16(pa0, tb, z, 0, 0, 0);
            #pragma unroll
            for (int r = 0; r < 4; ++r)
                Dst[(m0 + 4 * q + r) * DSTR + j0 + n16] = ps0[r] + tq - 2.f * d0[r];
        }
        __syncthreads();
        // anti-diagonal extraction for the 64x128 sub-tile:
        // local dp = row + jj in [0,190], span(jlo..jhi) <= 64 => one pass.
        const size_t dbase = ((size_t)b * NDG + a0 + 128 * h) * NS + 128 * h;
        #pragma unroll 4
        for (int i = 0; i < 48; ++i) {
            int dp  = 4 * i + w;                    // 0..191 (191 empty)
            int jlo = dp > 63 ? dp - 63 : 0;
            int jhi = dp < 127 ? dp : 127;
            int jj  = jlo + lane;
            if (jj <= jhi) {
                unsigned short vv = f2bf(Dst[(dp - jj) * DSTR + jj]);
                Ddiag[dbase + (size_t)dp * NS + jj] = vv;
            }
        }
    }
}

// ---------------------------------------------------------------------------
// K2: single-wave DPs; DPP cross-lane; branch-free load streams.
// blocks 0..63:  CTC linear-FP64 (verified numerics), depth-32 queue,
//                full-group/remainder loop split, pow-2 rescale every 8 steps.
// blocks 64..127: SoftDTW hard-min wavefront, bf16 cost reads, depth-32 queue.
// (byte-identical to the round-2 version that measured 85 us)
// ---------------------------------------------------------------------------
__global__ __launch_bounds__(64, 1) void k_dp(
    const float* __restrict__ lp, const int* __restrict__ tgt,
    const int* __restrict__ ilen, const int* __restrict__ tlen,
    const unsigned short* __restrict__ Ddiag, const unsigned short* __restrict__ Gbf,
    const float* __restrict__ PB, float* __restrict__ ctc_out,
    float* __restrict__ sdtw_out)
{
    __shared__ double smd[513];
    const int lane = threadIdx.x;
    const int bid = blockIdx.x;

    if (bid < NB) {
        // ------------------------- CTC, linear fp64 -------------------------
        const int b  = bid;
        const int len = ilen[b];          // wave-uniform (768..1024)
        const int tl  = tlen[b];
        const float* lpb = lp + (size_t)b * NT * NV;
        const unsigned short* Gb = Gbf + ((size_t)(b * NT) << 8);
        const float* PBb = PB + b * NT;

        const int4 t4 = ((const int4*)(tgt + b * NS))[lane];
        const int prevw = __shfl_up(t4.w, 1);
        const double m1d = ((lane > 0) && (t4.x != prevw)) ? 1.0 : 0.0;
        const double m3d = (t4.y != t4.x) ? 1.0 : 0.0;
        const double m5d = (t4.z != t4.y) ? 1.0 : 0.0;
        const double m7d = (t4.w != t4.z) ? 1.0 : 0.0;

        double a0 = 0.0, a1 = 0.0, a2 = 0.0, a3 = 0.0, a4 = 0.0,
               a5 = 0.0, a6 = 0.0, a7 = 0.0, a8 = 0.0;
        if (lane == 0) {
            a0 = (double)__expf(lpb[0]);
            a1 = (double)__expf(lpb[t4.x]);
        }
        long long Ksum = 0;

        auto ctc_step = [&](const ushort4 gu, const float pbf) {
            const double pb = (double)pbf;
            const double p0 = (double)bf2f(gu.x), p1 = (double)bf2f(gu.y);
            const double p2 = (double)bf2f(gu.z), p3 = (double)bf2f(gu.w);
            const double l7 = dpp_shr1_zero_f64(a7);
            const double n0 = (a0 + l7) * pb;
            const double n1 = fma(m1d, l7, a1 + a0) * p0;
            const double n2 = (a2 + a1) * pb;
            const double n3 = fma(m3d, a1, a3 + a2) * p1;
            const double n4 = (a4 + a3) * pb;
            const double n5 = fma(m5d, a3, a5 + a4) * p2;
            const double n6 = (a6 + a5) * pb;
            const double n7 = fma(m7d, a5, a7 + a6) * p3;
            const double n8 = (a8 + a7) * pb;
            a0 = n0; a1 = n1; a2 = n2; a3 = n3; a4 = n4;
            a5 = n5; a6 = n6; a7 = n7; a8 = n8;
        };
        auto ctc_rescale = [&]() {
            double m = fmax(a0, a1);
            m = fmax(m, a2); m = fmax(m, a3); m = fmax(m, a4);
            m = fmax(m, a5); m = fmax(m, a6); m = fmax(m, a7);
            m = fmax(m, a8);
            int Eb = (__double2hiint(m) >> 20) & 0x7ff;
            int Ex = wave_imax_dpp(Eb);
            if (Ex < 1) Ex = 1;
            const double inv = __hiloint2double((2046 - Ex) << 20, 0); // 2^(1023-Ex)
            Ksum += (long long)(Ex - 1023);
            a0 *= inv; a1 *= inv; a2 *= inv; a3 *= inv; a4 *= inv;
            a5 *= inv; a6 *= inv; a7 *= inv; a8 *= inv;
        };

        ushort4 gq[32];
        float   pbq[32];
        #pragma unroll
        for (int q = 0; q < 32; ++q) {
            gq[q]  = *(const ushort4*)(Gb + (((size_t)(1 + q)) << 8) + 4 * lane);
            pbq[q] = PBb[1 + q];
        }

        int t0 = 1;
        for (; t0 + 32 <= len; t0 += 32) {      // full groups: no per-step branch
            #pragma unroll
            for (int u = 0; u < 32; ++u) {
                const int t = t0 + u;
                const ushort4 gu = gq[u];
                const float pbf  = pbq[u];
                int tn = t + 32; if (tn > NT - 1) tn = NT - 1;
                gq[u]  = *(const ushort4*)(Gb + (((size_t)tn) << 8) + 4 * lane);
                pbq[u] = PBb[tn];
                ctc_step(gu, pbf);
                if ((u & 7) == 7) ctc_rescale();
            }
        }
        {   // remainder (< 32 steps), consume-only
            #pragma unroll
            for (int u = 0; u < 32; ++u) {
                if (t0 + u < len) ctc_step(gq[u], pbq[u]);
                if (u == 7 || u == 15 || u == 23) ctc_rescale();
            }
        }

        smd[lane * 8 + 0] = a0; smd[lane * 8 + 1] = a1;
        smd[lane * 8 + 2] = a2; smd[lane * 8 + 3] = a3;
        smd[lane * 8 + 4] = a4; smd[lane * 8 + 5] = a5;
        smd[lane * 8 + 6] = a6; smd[lane * 8 + 7] = a7;
        if (lane == 63) smd[512] = a8;
        __syncthreads();
        if (lane == 0) {
            const int l = 2 * tl + 1;
            const double s = smd[l - 1] + smd[l - 2];
            const double ll = (double)Ksum * 0.6931471805599453 + log(s);
            ctc_out[b] = (float)(-ll / (double)tl);
        }
    } else {
        // ------------- SoftDTW, hard-min wavefront, bf16 costs -------------
        const int b = bid - NB;
        const unsigned short* Db = Ddiag + (size_t)b * NDG * NS;

        float rp10 = BIGV, rp11 = BIGV, rp12 = BIGV, rp13 = BIGV;
        float rp20 = BIGV, rp21 = BIGV, rp22 = BIGV, rp23 = BIGV;
        if (lane == 0) rp10 = bf2f(Db[0]);

        ushort4 dq[32];
        #pragma unroll
        for (int q = 0; q < 32; ++q)
            dq[q] = *(const ushort4*)(Db + (size_t)(1 + q) * NS + 4 * lane);

        float res = 0.f;
        for (int d0 = 1; d0 < 1279; d0 += 32) {
            #pragma unroll
            for (int u = 0; u < 32; ++u) {
                const int d = d0 + u;
                const ushort4 Dv = dq[u];
                int dn = d + 32; if (dn > NDG - 1) dn = NDG - 1;
                dq[u] = *(const ushort4*)(Db + (size_t)dn * NS + 4 * lane);

                const float Dx = bf2f(Dv.x), Dy = bf2f(Dv.y);
                const float Dz = bf2f(Dv.z), Dw = bf2f(Dv.w);

                const float lf1 = dpp_shr1_f32(rp13, BIGV);
                const float lf2 = dpp_shr1_f32(rp23, BIGV);

                const float c0 = Dx + fminf(fminf(rp10, lf1),  lf2);
                const float c1 = Dy + fminf(fminf(rp11, rp10), rp20);
                const float c2 = Dz + fminf(fminf(rp12, rp11), rp21);
                const float c3 = Dw + fminf(fminf(rp13, rp12), rp22);

                rp20 = rp10; rp21 = rp11; rp22 = rp12; rp23 = rp13;
                rp10 = c0;   rp11 = c1;   rp12 = c2;   rp13 = c3;

                res = (d == NDG - 1) ? c3 : res;
            }
        }
        if (lane == 63) sdtw_out[b] = res;
    }
}

// ---------------------------------------------------------------------------
// K3: final scalar = mean(ctc) + mean(sdtw)
// ---------------------------------------------------------------------------
__global__ __launch_bounds__(64) void k_final(
    const float* __restrict__ ctc_out, const float* __restrict__ sdtw_out,
    float* __restrict__ out)
{
    int lane = threadIdx.x;
    float c = ctc_out[lane];
    float s = sdtw_out[lane];
    #pragma unroll
    for (int off = 32; off > 0; off >>= 1) {
        c += __shfl_down(c, off);
        s += __shfl_down(s, off);
    }
    if (lane == 0) out[0] = c / 64.f + s / 64.f;
}

extern "C" void kernel_launch(void* const* d_in, const int* in_sizes, int n_in,
                              void* d_out, int out_size, void* d_ws, size_t ws_size,
                              hipStream_t stream) {
    const float* lp   = (const float*)d_in[0];
    const float* fm   = (const float*)d_in[1];
    const int*   tgt  = (const int*)d_in[2];
    const int*   ilen = (const int*)d_in[3];
    const int*   tlen = (const int*)d_in[4];
    float* out = (float*)d_out;

    // ws layout: Ddiag bf16 (41.9 MB) | Gbf bf16 (32 MB) | PB (256 KB) | results
    char* ws = (char*)d_ws;
    unsigned short* Ddiag = (unsigned short*)ws;
    size_t dbytes = (size_t)NB * NDG * NS * sizeof(unsigned short); // 41,910,272
    unsigned short* Gbf = (unsigned short*)(ws + dbytes);
    size_t gbytes = (size_t)NB * NT * NS * sizeof(unsigned short);  // 33,554,432
    float* PB = (float*)(ws + dbytes + gbytes);
    size_t pbytes = (size_t)NB * NT * sizeof(float);                // 262,144
    float* ctc_res  = (float*)(ws + dbytes + gbytes + pbytes);
    float* sdtw_res = ctc_res + 64;

    hipLaunchKernelGGL(k_dmat, dim3(NB * 16), dim3(256), 0, stream,
                       lp, fm, tgt, Ddiag, Gbf, PB);
    hipLaunchKernelGGL(k_dp, dim3(2 * NB), dim3(64), 0, stream,
                       lp, tgt, ilen, tlen, Ddiag, Gbf, PB, ctc_res, sdtw_res);
    hipLaunchKernelGGL(k_final, dim3(1), dim3(64), 0, stream, ctc_res, sdtw_res, out);
}